// Round 7
// baseline (56.740 us; speedup 1.0000x reference)
//
#include <hip/hip_runtime.h>
#include <math.h>

// N=512, IN_F=128, OUT_F=64, H=4.
// DIAGNOSTIC ROUND: identical kernels to round 6, pipeline launched TWICE
// (idempotent) to separate fixed graph overhead from marginal per-pass cost:
//   marginal = T2 - T1_round6 ;  fixed = 2*T1_round6 - T2

__device__ __forceinline__ float wave_sum(float v) {
    #pragma unroll
    for (int o = 32; o; o >>= 1) v += __shfl_xor(v, o, 64);
    return v;
}
__device__ __forceinline__ float wave_max(float v) {
    #pragma unroll
    for (int o = 32; o; o >>= 1) v = fmaxf(v, __shfl_xor(v, o, 64));
    return v;
}
__device__ __forceinline__ unsigned bf16rn(float x) {   // round-to-nearest-even bf16
    unsigned u = __float_as_uint(x);
    return (u + 0x7fffu + ((u >> 16) & 1u)) >> 16;
}
__device__ __forceinline__ float asf(unsigned u) { return __uint_as_float(u); }

// ---------------- K1: ht = h @ W^T, plus s1, s2 ----------------
__global__ __launch_bounds__(256) void k_transform(
    const float* __restrict__ h, const float* __restrict__ W,
    const float* __restrict__ a,
    float* __restrict__ ht, float* __restrict__ s1, float* __restrict__ s2p)
{
    __shared__ float hsh[2 * 128];
    __shared__ float ash[512];      // a[4][128]
    __shared__ float hts[2 * 256];  // this block's ht rows
    const int t = threadIdx.x;
    const int i0 = blockIdx.x * 2;
    if (t < 64)       ((float4*)hsh)[t]      = ((const float4*)(h + i0 * 128))[t];
    else if (t < 192) ((float4*)ash)[t - 64] = ((const float4*)a)[t - 64];
    __syncthreads();

    float acc0 = 0.f, acc1 = 0.f;
    const float4* Wv = (const float4*)(W + t * 128);
    #pragma unroll
    for (int kk = 0; kk < 32; ++kk) {
        float4 w4 = Wv[kk];
        const float* h0 = hsh + kk * 4;
        const float* h1 = hsh + 128 + kk * 4;
        acc0 += w4.x * h0[0] + w4.y * h0[1] + w4.z * h0[2] + w4.w * h0[3];
        acc1 += w4.x * h1[0] + w4.y * h1[1] + w4.z * h1[2] + w4.w * h1[3];
    }
    ht[i0 * 256 + t]       = acc0;
    ht[(i0 + 1) * 256 + t] = acc1;
    hts[t]       = acc0;
    hts[256 + t] = acc1;
    __syncthreads();

    if (t < 40) {
        const int rr = t & 1, o = t >> 1;
        const float* x;
        const float* y;
        if (o < 16) { x = hts + rr * 256 + (o >> 2) * 64;  y = ash + (o & 3) * 128; }
        else        { x = hts + rr * 256 + (o - 16) * 64;  y = ash + (o - 16) * 128 + 64; }
        float s = 0.f;
        #pragma unroll
        for (int ff = 0; ff < 64; ++ff) {
            int f = (ff + (t << 3)) & 63;   // bank stagger
            s += x[f] * y[f];
        }
        if (o < 16) s1[(i0 + rr) * 16 + (o >> 2) * 4 + (o & 3)] = s;
        else        s2p[(o - 16) * 512 + i0 + rr] = s;
    }
}

// ---------------- K2: attention + aggregate (round-6 proven) ----------------
__global__ __launch_bounds__(512) void k_att(
    const int* __restrict__ adj, const float* __restrict__ ew,
    const float* __restrict__ ht, const float* __restrict__ s1,
    const float* __restrict__ s2p, float* __restrict__ c)
{
    __shared__ float scores[4 * 512];
    __shared__ unsigned attw[4 * 256];
    __shared__ float s2sh[512];
    __shared__ float s1sh[16];
    __shared__ float mloc[8], sloc[8];
    const int t = threadIdx.x;
    const int hh = blockIdx.x & 3;
    const int i0 = (blockIdx.x >> 2) * 4;

    s2sh[t] = s2p[hh * 512 + t];
    if (t < 16) s1sh[t] = s1[(i0 + (t >> 2)) * 16 + (t & 3) * 4 + hh];
    __syncthreads();

    {
        const int r = t >> 7, j4 = (t & 127) * 4;
        const float s1v = s1sh[r * 4 + (j4 >> 7)];
        int4   av = *(const int4*)  (adj + (i0 + r) * 512 + j4);
        float4 wv = *(const float4*)(ew  + (i0 + r) * 512 + j4);
        float4 sv = *(const float4*)&s2sh[j4];
        float4 o; float e;
        e = s1v + sv.x; e = (e >= 0.f) ? e : 0.2f * e; e *= wv.x; o.x = (av.x > 0) ? e : -9.0e15f;
        e = s1v + sv.y; e = (e >= 0.f) ? e : 0.2f * e; e *= wv.y; o.y = (av.y > 0) ? e : -9.0e15f;
        e = s1v + sv.z; e = (e >= 0.f) ? e : 0.2f * e; e *= wv.z; o.z = (av.z > 0) ? e : -9.0e15f;
        e = s1v + sv.w; e = (e >= 0.f) ? e : 0.2f * e; e *= wv.w; o.w = (av.w > 0) ? e : -9.0e15f;
        *(float4*)&scores[r * 512 + j4] = o;
    }
    __syncthreads();

    const int w = t >> 6, lane = t & 63;
    {
        const int r = w >> 1, jh = w & 1;
        float4 v4 = *(const float4*)&scores[r * 512 + jh * 256 + lane * 4];
        float m = fmaxf(fmaxf(v4.x, v4.y), fmaxf(v4.z, v4.w));
        m = wave_max(m);
        if (lane == 0) mloc[w] = m;
        __syncthreads();
        m = fmaxf(mloc[r * 2], mloc[r * 2 + 1]);
        float e0 = __expf(v4.x - m), e1 = __expf(v4.y - m);
        float e2 = __expf(v4.z - m), e3 = __expf(v4.w - m);
        float s = wave_sum((e0 + e1) + (e2 + e3));
        if (lane == 0) sloc[w] = s;
        uint2 pk;
        pk.x = bf16rn(e0) | (bf16rn(e1) << 16);
        pk.y = bf16rn(e2) | (bf16rn(e3) << 16);
        *(uint2*)&attw[r * 256 + jh * 128 + lane * 2] = pk;
    }
    __syncthreads();

    float pacc[4] = {0.f, 0.f, 0.f, 0.f};
    const float* htp = ht + hh * 64 + lane;
    const int jbase = w * 64;
    for (int g = 0; g < 8; ++g) {
        const int j = jbase + g * 8;
        float hv[8];
        #pragma unroll
        for (int q = 0; q < 8; ++q) hv[q] = htp[(j + q) * 256];
        #pragma unroll
        for (int r = 0; r < 4; ++r) {
            uint4 av = *(const uint4*)&attw[r * 256 + (j >> 1)];
            pacc[r] += asf(av.x << 16) * hv[0] + asf(av.x & 0xffff0000u) * hv[1]
                     + asf(av.y << 16) * hv[2] + asf(av.y & 0xffff0000u) * hv[3]
                     + asf(av.z << 16) * hv[4] + asf(av.z & 0xffff0000u) * hv[5]
                     + asf(av.w << 16) * hv[6] + asf(av.w & 0xffff0000u) * hv[7];
        }
    }
    __syncthreads();
    #pragma unroll
    for (int r = 0; r < 4; ++r) scores[w * 256 + r * 64 + lane] = pacc[r];
    __syncthreads();
    if (t < 256) {
        const int r = t >> 6, f = t & 63;
        float s = 0.f;
        #pragma unroll
        for (int w8 = 0; w8 < 8; ++w8) s += scores[w8 * 256 + r * 64 + f];
        float inv = 1.f / (sloc[r * 2] + sloc[r * 2 + 1]);
        c[(i0 + r) * 256 + hh * 64 + f] = s * inv;
    }
}

// ---------------- K3: out = sigmoid(h U^T + c V^T) (round-5 proven) ----------------
__global__ __launch_bounds__(512) void k_out(
    const float* __restrict__ h, const float* __restrict__ cbuf,
    const float* __restrict__ U, const float* __restrict__ V,
    float* __restrict__ out)
{
    __shared__ float hsh[4 * 128];
    __shared__ float csh[4 * 256];
    __shared__ float psum[2 * 4 * 256];   // [half][row][col]
    const int t = threadIdx.x;
    const int i0 = blockIdx.x * 4;
    if (t < 128)      ((float4*)hsh)[t]       = ((const float4*)(h + i0 * 128))[t];
    else if (t < 384) ((float4*)csh)[t - 128] = ((const float4*)(cbuf + i0 * 256))[t - 128];
    __syncthreads();

    const int col = t & 255, half = t >> 8;
    float acc[4] = {0.f, 0.f, 0.f, 0.f};
    {
        const float4* Uv = (const float4*)(U + col * 128 + half * 64);
        #pragma unroll
        for (int kk = 0; kk < 16; ++kk) {
            float4 u4 = Uv[kk];
            const int k0 = half * 64 + kk * 4;
            #pragma unroll
            for (int r = 0; r < 4; ++r) {
                const float* hp = hsh + r * 128 + k0;
                acc[r] += u4.x * hp[0] + u4.y * hp[1] + u4.z * hp[2] + u4.w * hp[3];
            }
        }
        const float4* Vv = (const float4*)(V + col * 256 + half * 128);
        #pragma unroll
        for (int kk = 0; kk < 32; ++kk) {
            float4 v4 = Vv[kk];
            const int k0 = half * 128 + kk * 4;
            #pragma unroll
            for (int r = 0; r < 4; ++r) {
                const float* cp = csh + r * 256 + k0;
                acc[r] += v4.x * cp[0] + v4.y * cp[1] + v4.z * cp[2] + v4.w * cp[3];
            }
        }
    }
    #pragma unroll
    for (int r = 0; r < 4; ++r) psum[(half * 4 + r) * 256 + col] = acc[r];
    __syncthreads();
    {
        const int rr = t >> 8;
        #pragma unroll
        for (int q = 0; q < 2; ++q) {
            const int r = rr * 2 + q;
            float x = psum[r * 256 + col] + psum[(4 + r) * 256 + col];
            out[(i0 + r) * 256 + col] = 1.f / (1.f + __expf(-x));
        }
    }
}

extern "C" void kernel_launch(void* const* d_in, const int* in_sizes, int n_in,
                              void* d_out, int out_size, void* d_ws, size_t ws_size,
                              hipStream_t stream) {
    const float* h   = (const float*)d_in[0];
    const int*   adj = (const int*)d_in[1];
    const float* ew  = (const float*)d_in[2];
    const float* W   = (const float*)d_in[3];
    const float* a   = (const float*)d_in[4];
    const float* U   = (const float*)d_in[5];
    const float* V   = (const float*)d_in[6];
    float* out = (float*)d_out;

    float* ht  = (float*)d_ws;           // 512*256
    float* s1  = ht + 512 * 256;         // 512*16
    float* s2p = s1 + 512 * 16;          // 4*512
    float* c   = s2p + 4 * 512;          // 512*256

    // Pass 1
    k_transform<<<256, 256, 0, stream>>>(h, W, a, ht, s1, s2p);
    k_att<<<512, 512, 0, stream>>>(adj, ew, ht, s1, s2p, c);
    k_out<<<128, 512, 0, stream>>>(h, c, U, V, out);
    // Pass 2 (identical, idempotent) — diagnostic: marginal pass cost
    k_transform<<<256, 256, 0, stream>>>(h, W, a, ht, s1, s2p);
    k_att<<<512, 512, 0, stream>>>(adj, ew, ht, s1, s2p, c);
    k_out<<<128, 512, 0, stream>>>(h, c, U, V, out);
}

// Round 8
// 31.778 us; speedup vs baseline: 1.7855x; 1.7855x over previous
//
#include <hip/hip_runtime.h>
#include <math.h>

// N=512, IN_F=128, OUT_F=64, H=4.
// Two-node pipeline (node boundary = the one true global dependency):
//   K1: ht=h@W^T -> htb (bf16 j-pair packed) + s1,s2 score projections
//   K2: scores -> softmax -> aggregate (bf16 MACs) -> fused U/V epilogue -> out
// e_raw[i,j,h] = s1[i][j>>7][h] + s2[j][h]; leaky(0.2), *ew, mask adj,
// softmax_j; c[i,h,f] = sum_j alpha*ht[j,h,f]; out = sigmoid(h U^T + c V^T).

__device__ __forceinline__ float wave_sum(float v) {
    #pragma unroll
    for (int o = 32; o; o >>= 1) v += __shfl_xor(v, o, 64);
    return v;
}
__device__ __forceinline__ float wave_max(float v) {
    #pragma unroll
    for (int o = 32; o; o >>= 1) v = fmaxf(v, __shfl_xor(v, o, 64));
    return v;
}
__device__ __forceinline__ unsigned bf16rn(float x) {   // round-to-nearest-even bf16
    unsigned u = __float_as_uint(x);
    return (u + 0x7fffu + ((u >> 16) & 1u)) >> 16;
}
__device__ __forceinline__ float asf(unsigned u) { return __uint_as_float(u); }

// ---------------- K1: htb = pack(h @ W^T rows 2b,2b+1), plus s1, s2 ----------------
// 256 blocks x 256 thr. Block b handles rows 2b, 2b+1 == j-pair b.
__global__ __launch_bounds__(256) void k_transform(
    const float* __restrict__ h, const float* __restrict__ W,
    const float* __restrict__ a,
    unsigned* __restrict__ htb, float* __restrict__ s1, float* __restrict__ s2p)
{
    __shared__ float hsh[2 * 128];
    __shared__ float ash[512];      // a[4][128]
    __shared__ float hts[2 * 256];  // this block's ht rows (f32, for s1/s2)
    const int t = threadIdx.x;
    const int i0 = blockIdx.x * 2;
    if (t < 64)       ((float4*)hsh)[t]      = ((const float4*)(h + i0 * 128))[t];
    else if (t < 192) ((float4*)ash)[t - 64] = ((const float4*)a)[t - 64];
    __syncthreads();

    float acc0 = 0.f, acc1 = 0.f;
    const float4* Wv = (const float4*)(W + t * 128);
    #pragma unroll
    for (int kk = 0; kk < 32; ++kk) {
        float4 w4 = Wv[kk];
        const float* h0 = hsh + kk * 4;
        const float* h1 = hsh + 128 + kk * 4;
        acc0 += w4.x * h0[0] + w4.y * h0[1] + w4.z * h0[2] + w4.w * h0[3];
        acc1 += w4.x * h1[0] + w4.y * h1[1] + w4.z * h1[2] + w4.w * h1[3];
    }
    // bf16 j-pair pack: low = row 2b (j even), high = row 2b+1 (j odd)
    htb[blockIdx.x * 256 + t] = bf16rn(acc0) | (bf16rn(acc1) << 16);
    hts[t]       = acc0;
    hts[256 + t] = acc1;
    __syncthreads();

    if (t < 40) {
        const int rr = t & 1, o = t >> 1;
        const float* x;
        const float* y;
        if (o < 16) { x = hts + rr * 256 + (o >> 2) * 64;  y = ash + (o & 3) * 128; }
        else        { x = hts + rr * 256 + (o - 16) * 64;  y = ash + (o - 16) * 128 + 64; }
        float s = 0.f;
        #pragma unroll
        for (int ff = 0; ff < 64; ++ff) {
            int f = (ff + (t << 3)) & 63;   // bank stagger
            s += x[f] * y[f];
        }
        if (o < 16) s1[(i0 + rr) * 16 + (o >> 2) * 4 + (o & 3)] = s;
        else        s2p[(o - 16) * 512 + i0 + rr] = s;
    }
}

// ---------------- K2: fused attention + aggregate + output ----------------
// 256 blocks x 512 thr (8 waves), block = 2 output rows x ALL 4 heads.
__global__ __launch_bounds__(512) void k_fused(
    const int* __restrict__ adj, const float* __restrict__ ew,
    const unsigned* __restrict__ htb, const float* __restrict__ s1,
    const float* __restrict__ s2p, const float* __restrict__ h,
    const float* __restrict__ U, const float* __restrict__ V,
    float* __restrict__ out)
{
    __shared__ float scores[8 * 512];    // [(r*4+h)][j]        16 KB
    __shared__ unsigned attw[8 * 256];   // [(r*4+h)][jp] bf16x2 8 KB
    __shared__ float s2sh[4 * 512];      // [h][j]               8 KB
    __shared__ float s1sh[32];           // [r][g][h]
    __shared__ float invsh[8];           // [(r*4+h)]
    __shared__ float part[2 * 512];      // [jh][(r*4+h)*64+lane] 4 KB
    __shared__ float hsh[2 * 128];       // h rows i0, i0+1
    __shared__ float csh[2 * 256];       // c rows
    __shared__ float psum[4 * 256];      // [(half*2+r)][col]    4 KB

    const int t = threadIdx.x;
    const int i0 = blockIdx.x * 2;

    ((float4*)s2sh)[t] = ((const float4*)s2p)[t];             // 2048 floats
    if (t < 32) s1sh[t] = s1[(i0 + (t >> 4)) * 16 + (t & 15)];
    if (t >= 448) ((float4*)hsh)[t - 448] = ((const float4*)(h + i0 * 128))[t - 448];
    __syncthreads();

    // ---- scores: thread = (row r, 2 consecutive j), all 4 heads ----
    {
        const int r = t >> 8, j2 = (t & 255) * 2;
        int2   av = *(const int2*)  (adj + (i0 + r) * 512 + j2);
        float2 wv = *(const float2*)(ew  + (i0 + r) * 512 + j2);
        const int g4 = (j2 >> 7) * 4;
        #pragma unroll
        for (int hq = 0; hq < 4; ++hq) {
            float s1v = s1sh[r * 16 + g4 + hq];
            float2 sv = *(const float2*)&s2sh[hq * 512 + j2];
            float e0 = s1v + sv.x, e1 = s1v + sv.y;
            e0 = (e0 >= 0.f) ? e0 : 0.2f * e0;  e0 *= wv.x;  e0 = (av.x > 0) ? e0 : -9.0e15f;
            e1 = (e1 >= 0.f) ? e1 : 0.2f * e1;  e1 *= wv.y;  e1 = (av.y > 0) ? e1 : -9.0e15f;
            *(float2*)&scores[(r * 4 + hq) * 512 + j2] = make_float2(e0, e1);
        }
    }
    __syncthreads();

    // ---- softmax: wave w owns row (r = w>>2, h = w&3); lane = 4 j-pairs ----
    const int w = t >> 6, lane = t & 63;
    {
        float v[8];
        #pragma unroll
        for (int k = 0; k < 4; ++k) {
            float2 f2 = *(const float2*)&scores[w * 512 + lane * 2 + k * 128];
            v[2 * k] = f2.x;  v[2 * k + 1] = f2.y;
        }
        float m = v[0];
        #pragma unroll
        for (int k = 1; k < 8; ++k) m = fmaxf(m, v[k]);
        m = wave_max(m);
        float s = 0.f;
        #pragma unroll
        for (int k = 0; k < 8; ++k) { v[k] = __expf(v[k] - m); s += v[k]; }
        s = wave_sum(s);
        if (lane == 0) invsh[w] = 1.f / s;
        #pragma unroll
        for (int k = 0; k < 4; ++k)
            attw[w * 256 + lane + k * 64] = bf16rn(v[2 * k]) | (bf16rn(v[2 * k + 1]) << 16);
    }
    __syncthreads();

    // ---- aggregate: wave w = (head hh = w&3, j-half jh = w>>2), both rows ----
    {
        const int hh = w & 3, jh = w >> 2;
        float p0 = 0.f, p1 = 0.f;
        const unsigned* hb = htb + hh * 64 + lane;
        const int jp0 = jh * 128;
        for (int q = 0; q < 128; q += 8) {
            unsigned hv[8];
            #pragma unroll
            for (int u = 0; u < 8; ++u) hv[u] = hb[(jp0 + q + u) * 256];
            unsigned a0arr[8], a1arr[8];
            *(uint4*)&a0arr[0] = *(const uint4*)&attw[hh * 256 + jp0 + q];
            *(uint4*)&a0arr[4] = *(const uint4*)&attw[hh * 256 + jp0 + q + 4];
            *(uint4*)&a1arr[0] = *(const uint4*)&attw[(4 + hh) * 256 + jp0 + q];
            *(uint4*)&a1arr[4] = *(const uint4*)&attw[(4 + hh) * 256 + jp0 + q + 4];
            #pragma unroll
            for (int u = 0; u < 8; ++u) {
                float hl = asf(hv[u] << 16), hhi = asf(hv[u] & 0xffff0000u);
                p0 += asf(a0arr[u] << 16) * hl + asf(a0arr[u] & 0xffff0000u) * hhi;
                p1 += asf(a1arr[u] << 16) * hl + asf(a1arr[u] & 0xffff0000u) * hhi;
            }
        }
        part[jh * 512 + hh * 64 + lane]       = p0;   // r=0
        part[jh * 512 + 256 + hh * 64 + lane] = p1;   // r=1
    }
    __syncthreads();

    // ---- combine partials -> c rows in LDS ----
    {
        const int r = t >> 8, cc = t & 255;            // cc = hh*64+lane
        const int hh2 = cc >> 6;
        float cv = (part[r * 256 + cc] + part[512 + r * 256 + cc]) * invsh[r * 4 + hh2];
        csh[r * 256 + cc] = cv;
    }
    __syncthreads();

    // ---- epilogue: out = sigmoid(h U^T + c V^T), K-split across halves ----
    {
        const int half = t >> 8, col = t & 255;
        float acc0 = 0.f, acc1 = 0.f;
        const float4* Uv = (const float4*)(U + col * 128 + half * 64);
        #pragma unroll
        for (int kk = 0; kk < 16; ++kk) {
            float4 u4 = Uv[kk];
            const float* h0 = hsh + half * 64 + kk * 4;
            const float* h1 = hsh + 128 + half * 64 + kk * 4;
            acc0 += u4.x * h0[0] + u4.y * h0[1] + u4.z * h0[2] + u4.w * h0[3];
            acc1 += u4.x * h1[0] + u4.y * h1[1] + u4.z * h1[2] + u4.w * h1[3];
        }
        const float4* Vv = (const float4*)(V + col * 256 + half * 128);
        #pragma unroll
        for (int kk = 0; kk < 32; ++kk) {
            float4 v4 = Vv[kk];
            const float* c0 = csh + half * 128 + kk * 4;
            const float* c1 = csh + 256 + half * 128 + kk * 4;
            acc0 += v4.x * c0[0] + v4.y * c0[1] + v4.z * c0[2] + v4.w * c0[3];
            acc1 += v4.x * c1[0] + v4.y * c1[1] + v4.z * c1[2] + v4.w * c1[3];
        }
        psum[(half * 2 + 0) * 256 + col] = acc0;
        psum[(half * 2 + 1) * 256 + col] = acc1;
    }
    __syncthreads();
    {
        const int r = t >> 8, col = t & 255;
        float x = psum[r * 256 + col] + psum[(2 + r) * 256 + col];
        out[(i0 + r) * 256 + col] = 1.f / (1.f + __expf(-x));
    }
}

extern "C" void kernel_launch(void* const* d_in, const int* in_sizes, int n_in,
                              void* d_out, int out_size, void* d_ws, size_t ws_size,
                              hipStream_t stream) {
    const float* h   = (const float*)d_in[0];
    const int*   adj = (const int*)d_in[1];
    const float* ew  = (const float*)d_in[2];
    const float* W   = (const float*)d_in[3];
    const float* a   = (const float*)d_in[4];
    const float* U   = (const float*)d_in[5];
    const float* V   = (const float*)d_in[6];
    float* out = (float*)d_out;

    unsigned* htb = (unsigned*)d_ws;          // 256*256 u32 (bf16 j-pairs)
    float* s1  = (float*)(htb + 256 * 256);   // 512*16
    float* s2p = s1 + 512 * 16;               // 4*512

    k_transform<<<256, 256, 0, stream>>>(h, W, a, htb, s1, s2p);
    k_fused<<<256, 512, 0, stream>>>(adj, ew, htb, s1, s2p, h, U, V, out);
}